// Round 18
// baseline (376.348 us; speedup 1.0000x reference)
//
#include <hip/hip_runtime.h>

#define NN 100000   // real nodes
#define NP 100096   // padded to 782*128
#define NE 600000   // edges
#define CC 128      // channels

typedef __attribute__((ext_vector_type(4))) float f32x4;
typedef _Float16 h8 __attribute__((ext_vector_type(8)));
typedef _Float16 h2 __attribute__((ext_vector_type(2)));

// H-region LDS granule perm: conflict-free for BOTH the C-write pattern (4 lk-groups
// -> 4 distinct bank octets) and the A-read pattern (uniform 8 dwords/bank).
__device__ __forceinline__ int pg(int R, int g) {
  return g ^ (R & 7) ^ (((R >> 2) & 3) << 1);
}

// ---------------- zero-init (replaces hipMemsetAsync: fillBufferAligned was 43µs
// for 800KB at 18.5 GB/s — pathological; this kernel is ~3µs) ----------------

#define DC_INT4 ((NP + NN) / 4)   // 200096 ints -> 50024 int4s

__global__ void k_zero(int4* __restrict__ dst) {
  int i = blockIdx.x * 256 + threadIdx.x;
  if (i < DC_INT4) dst[i] = make_int4(0, 0, 0, 0);
}

// ---------------- graph preprocessing ----------------

__global__ void k_deg(const int* __restrict__ col, int* __restrict__ deg) {
  int e = blockIdx.x * 256 + threadIdx.x;
  if (e < NE) atomicAdd(&deg[col[e]], 1);
}

// scan1 also emits dis[] (needs only deg[i], already loaded)
__global__ void k_scan1(const int* __restrict__ deg, int* __restrict__ rowptr,
                        int* __restrict__ bsum, float* __restrict__ dis) {
  __shared__ int s[1024];
  int t = threadIdx.x;
  int i = blockIdx.x * 1024 + t;
  int v = (i < NN) ? deg[i] : 0;
  if (i < NN) dis[i] = (v > 0) ? rsqrtf((float)v) : 0.0f;
  s[t] = v;
  __syncthreads();
  #pragma unroll
  for (int off = 1; off < 1024; off <<= 1) {
    int tv = (t >= off) ? s[t - off] : 0;
    __syncthreads();
    s[t] += tv;
    __syncthreads();
  }
  if (i < NN) rowptr[i] = s[t] - v;           // exclusive
  if (t == 1023) bsum[blockIdx.x] = s[1023];
}

// scan2 also writes the rowptr tail (padded nodes -> empty ranges)
__global__ void k_scan2(const int* __restrict__ bsum, int* __restrict__ bsum2,
                        int* __restrict__ rowptr) {
  int t = threadIdx.x;
  if (t < NP + 8 - NN) rowptr[NN + t] = NE;   // 104 entries
  __shared__ int s[128];
  int v = (t < 98) ? bsum[t] : 0;
  s[t] = v;
  __syncthreads();
  #pragma unroll
  for (int off = 1; off < 128; off <<= 1) {
    int tv = (t >= off) ? s[t - off] : 0;
    __syncthreads();
    s[t] += tv;
    __syncthreads();
  }
  bsum2[t] = s[t] - v;                        // exclusive
}

__global__ void k_scan3(int* __restrict__ rowptr, const int* __restrict__ bsum2) {
  int i = blockIdx.x * 1024 + threadIdx.x;
  if (i < NN) rowptr[i] += bsum2[blockIdx.x];
}

// packed CSR entry: {src_node*CC, float_bits(norm_w)} -> one 8B load per edge
__global__ void k_fill(const int* __restrict__ row, const int* __restrict__ col,
                       const float* __restrict__ dis, const int* __restrict__ rowptr,
                       int* __restrict__ cnt, int2* __restrict__ csr) {
  int e = blockIdx.x * 256 + threadIdx.x;
  if (e >= NE) return;
  int c = col[e], r = row[e];
  int pos = rowptr[c] + atomicAdd(&cnt[c], 1);
  int2 v;
  v.x = r * CC;
  v.y = __float_as_int(dis[r] * dis[c]);
  csr[pos] = v;
}

// ---------------- lin0: h = relu(x @ W0 + b0), x is [N,6], out fp16 ----------------

__global__ void k_lin0(const float* __restrict__ x, const float* __restrict__ W0,
                       const float* __restrict__ b0, _Float16* __restrict__ h) {
  int idx = blockIdx.x * 256 + threadIdx.x;   // n*128 + c
  int n = idx >> 7, c = idx & 127;
  if (n >= NP) return;
  float v = 0.0f;
  if (n < NN) {
    v = b0[c];
    #pragma unroll
    for (int f = 0; f < 6; ++f) v = fmaf(x[n * 6 + f], W0[f * CC + c], v);
    v = fmaxf(v, 0.0f);
  }
  h[idx] = (_Float16)v;
}

// ---------------- W conversion (both weight sets in one launch) ----------------
// fp32 [K][128] -> fp16 MFMA-B-permuted; dst = WpT (1024 rows) || WpM (256 rows)

__global__ void k_wconv2(const float* __restrict__ srcT, const float* __restrict__ srcM,
                         _Float16* __restrict__ dst) {
  int tid0 = blockIdx.x * 256 + threadIdx.x;
  if (tid0 >= 1280 * 128) return;
  const float* src = srcT;
  int tid = tid0;
  if (tid0 >= 1024 * 128) { src = srcM; tid = tid0 - 1024 * 128; }
  int e = tid & 7, l = (tid >> 3) & 63, nb = (tid >> 9) & 7, kb = tid >> 12;
  int k = kb * 32 + (l >> 4) * 8 + e;
  int c = nb * 16 + (l & 15);
  dst[tid0] = (_Float16)src[k * 128 + c];
}

// ---------------- propagation: 4 nodes/wave, contiguous CSR, 8-deep gather MLP ----
// (round-10 variant: best measured; r11 16-lane-gather −22µs, r13 sw-pipeline −58µs)

__global__ __launch_bounds__(256) void k_prop(const int* __restrict__ rowptr,
                                              const int2* __restrict__ csr,
                                              const _Float16* __restrict__ xin,
                                              _Float16* __restrict__ xout) {
  int gid = blockIdx.x * 256 + threadIdx.x;
  int wv = gid >> 6;             // wave -> nodes 4*wv .. 4*wv+3
  int lane = gid & 63;
  int n0 = wv * 4;
  if (n0 >= NP) return;
  int b0 = rowptr[n0], b1 = rowptr[n0 + 1], b2 = rowptr[n0 + 2],
      b3 = rowptr[n0 + 3], b4 = rowptr[n0 + 4];
  int e4 = b4 - b0;

  int2 ew; ew.x = 0; ew.y = 0;   // w=0 padding: contributes nothing, gathers node 0
  int gl = 0;
  if (lane < e4) {
    int pos = b0 + lane;
    ew = csr[pos];
    gl = (pos >= b1) + (pos >= b2) + (pos >= b3);
  }

  float a00 = 0, a01 = 0, a10 = 0, a11 = 0, a20 = 0, a21 = 0, a30 = 0, a31 = 0;
  int nb = e4 < 64 ? e4 : 64;
  for (int j = 0; j < nb; j += 8) {
    #pragma unroll
    for (int u = 0; u < 8; ++u) {
      int off = __shfl(ew.x, j + u);
      float w = __uint_as_float(__shfl(ew.y, j + u));
      int gg = __shfl(gl, j + u);
      h2 v = *reinterpret_cast<const h2*>(&xin[off + lane * 2]);
      float v0 = (float)v[0], v1 = (float)v[1];
      float w0 = (gg == 0) ? w : 0.0f;
      float w1 = (gg == 1) ? w : 0.0f;
      float w2 = (gg == 2) ? w : 0.0f;
      float w3 = (gg == 3) ? w : 0.0f;
      a00 += w0 * v0; a01 += w0 * v1;
      a10 += w1 * v0; a11 += w1 * v1;
      a20 += w2 * v0; a21 += w2 * v1;
      a30 += w3 * v0; a31 += w3 * v1;
    }
  }
  for (int j = 64; j < e4; ++j) {              // astronomically rare tail
    int pos = b0 + j;
    int2 e2 = csr[pos];
    float w = __uint_as_float(e2.y);
    int gg = (pos >= b1) + (pos >= b2) + (pos >= b3);
    h2 v = *reinterpret_cast<const h2*>(&xin[e2.x + lane * 2]);
    float v0 = (float)v[0], v1 = (float)v[1];
    float w0 = (gg == 0) ? w : 0.0f;
    float w1 = (gg == 1) ? w : 0.0f;
    float w2 = (gg == 2) ? w : 0.0f;
    float w3 = (gg == 3) ? w : 0.0f;
    a00 += w0 * v0; a01 += w0 * v1;
    a10 += w1 * v0; a11 += w1 * v1;
    a20 += w2 * v0; a21 += w2 * v1;
    a30 += w3 * v0; a31 += w3 * v1;
  }

  h2 o;
  o[0] = (_Float16)a00; o[1] = (_Float16)a01;
  *reinterpret_cast<h2*>(&xout[(size_t)(n0 + 0) * CC + lane * 2]) = o;
  o[0] = (_Float16)a10; o[1] = (_Float16)a11;
  *reinterpret_cast<h2*>(&xout[(size_t)(n0 + 1) * CC + lane * 2]) = o;
  o[0] = (_Float16)a20; o[1] = (_Float16)a21;
  *reinterpret_cast<h2*>(&xout[(size_t)(n0 + 2) * CC + lane * 2]) = o;
  o[0] = (_Float16)a30; o[1] = (_Float16)a31;
  *reinterpret_cast<h2*>(&xout[(size_t)(n0 + 3) * CC + lane * 2]) = o;
}

// ---------------- MFMA GEMM: Y = relu?(cat(X0..X3) @ Wp + bias), double-buffered ----
// 4 waves, 128x128 tile. Stage tile xi+1 while computing xi; counted vmcnt(8) keeps
// next tile's 8 global_load_lds in flight across the barrier (never drain to 0 mid-loop).

template<int KB, bool BR>
__global__ __launch_bounds__(256) void k_mm(const _Float16* __restrict__ X0,
                                            const _Float16* __restrict__ X1,
                                            const _Float16* __restrict__ X2,
                                            const _Float16* __restrict__ X3,
                                            const _Float16* __restrict__ Wp,
                                            const float* __restrict__ bias,
                                            _Float16* __restrict__ Y) {
  __shared__ _Float16 lds[2][128 * 128];      // 2 x 32 KB
  int t = threadIdx.x;
  int w = t >> 6, l = t & 63;
  int lr = l & 15, lk = l >> 4;
  int m0w = (w & 1) * 64;
  int nb0 = (w >> 1) * 4;
  long row0 = (long)blockIdx.x * 128;
  const _Float16* Xs[4] = {X0, X1, X2, X3};

  auto stage = [&](int buf, const _Float16* __restrict__ xb) {
    #pragma unroll
    for (int i = 0; i < 8; ++i) {
      int li = i * 256 + t;                   // 16B-granule index 0..2047
      int r = li >> 4, ck = li & 15;
      int cs = ck ^ (r & 7);
      const _Float16* src = xb + (size_t)(row0 + r) * CC + cs * 8;
      _Float16* dst = &lds[buf][i * 2048 + (t & 192) * 8];  // wave-uniform base
      __builtin_amdgcn_global_load_lds((const __attribute__((address_space(1))) void*)src,
                                       (__attribute__((address_space(3))) void*)dst,
                                       16, 0, 0);
    }
  };

  f32x4 acc[4][4];
  #pragma unroll
  for (int m = 0; m < 4; ++m)
    #pragma unroll
    for (int n = 0; n < 4; ++n) acc[m][n] = (f32x4){0.f, 0.f, 0.f, 0.f};

  stage(0, Xs[0]);
  #pragma unroll
  for (int xi = 0; xi < KB; ++xi) {
    if (xi + 1 < KB) {
      stage((xi + 1) & 1, Xs[xi + 1]);
      asm volatile("s_waitcnt vmcnt(8)" ::: "memory");   // tile xi resident; xi+1 in flight
    } else {
      asm volatile("s_waitcnt vmcnt(0)" ::: "memory");
    }
    __builtin_amdgcn_sched_barrier(0);
    __builtin_amdgcn_s_barrier();
    const _Float16* __restrict__ lb = lds[xi & 1];

    #pragma unroll
    for (int kk = 0; kk < 4; ++kk) {
      int kb = xi * 4 + kk;
      h8 a[4], b[4];
      #pragma unroll
      for (int m = 0; m < 4; ++m) {
        int R = m0w + m * 16 + lr;
        a[m] = *reinterpret_cast<const h8*>(&lb[R * 128 + (((kk * 4 + lk) ^ (lr & 7)) << 3)]);
      }
      #pragma unroll
      for (int n = 0; n < 4; ++n)
        b[n] = *reinterpret_cast<const h8*>(&Wp[((size_t)(kb * 8 + nb0 + n) * 64 + l) * 8]);
      #pragma unroll
      for (int m = 0; m < 4; ++m)
        #pragma unroll
        for (int n = 0; n < 4; ++n)
          acc[m][n] = __builtin_amdgcn_mfma_f32_16x16x32_f16(a[m], b[n], acc[m][n], 0, 0, 0);
    }
    __builtin_amdgcn_s_barrier();             // reads done before next stage overwrites
  }

  // C/D layout: col = lane&15, row = (lane>>4)*4 + reg
  int r0 = m0w + lk * 4;
  long rb = row0 + r0;
  #pragma unroll
  for (int m = 0; m < 4; ++m) {
    #pragma unroll
    for (int n = 0; n < 4; ++n) {
      int c = (nb0 + n) * 16 + lr;
      float bv = BR ? bias[c] : 0.0f;
      #pragma unroll
      for (int q = 0; q < 4; ++q) {
        float v = acc[m][n][q] + bv;
        if (BR) v = fmaxf(v, 0.0f);
        Y[(rb + m * 16 + q) * CC + c] = (_Float16)v;
      }
    }
  }
}

// ---------------- fused tail: h1=relu(X@M0+b0'); h2=relu(h1@M1+b1'); out=relu(h2@W1+b1) ----
// one 128-row block; h1/h2 live in LDS with the pg() perm (conflict-free write AND read).

__global__ __launch_bounds__(256) void k_tail(const _Float16* __restrict__ X,
                                              const _Float16* __restrict__ WpM,
                                              const float* __restrict__ b_mlp,
                                              const float* __restrict__ W1,
                                              const float* __restrict__ b1,
                                              float* __restrict__ out) {
  __shared__ _Float16 lds[128 * 128];         // 32 KB
  int t = threadIdx.x;
  int w = t >> 6, l = t & 63;
  int lr = l & 15, lk = l >> 4;
  int m0w = (w & 1) * 64;
  int nb0 = (w >> 1) * 4;
  long row0 = (long)blockIdx.x * 128;

  // stage X tile (pre-swizzled source -> linear LDS; X-read perm = g ^ (r&7))
  #pragma unroll
  for (int i = 0; i < 8; ++i) {
    int li = i * 256 + t;
    int r = li >> 4, ck = li & 15;
    int cs = ck ^ (r & 7);
    const _Float16* src = X + (size_t)(row0 + r) * CC + cs * 8;
    _Float16* dst = &lds[i * 2048 + (t & 192) * 8];
    __builtin_amdgcn_global_load_lds((const __attribute__((address_space(1))) void*)src,
                                     (__attribute__((address_space(3))) void*)dst,
                                     16, 0, 0);
  }
  __syncthreads();

  f32x4 acc[4][4];
  #pragma unroll
  for (int ph = 0; ph < 2; ++ph) {
    #pragma unroll
    for (int m = 0; m < 4; ++m)
      #pragma unroll
      for (int n = 0; n < 4; ++n) acc[m][n] = (f32x4){0.f, 0.f, 0.f, 0.f};
    #pragma unroll
    for (int kk = 0; kk < 4; ++kk) {
      h8 a[4], b[4];
      #pragma unroll
      for (int m = 0; m < 4; ++m) {
        int R = m0w + m * 16 + lr;
        int g = kk * 4 + lk;
        int gp = (ph == 0) ? (g ^ (R & 7)) : pg(R, g);   // X-perm pass 0, H-perm pass 1
        a[m] = *reinterpret_cast<const h8*>(&lds[R * 128 + gp * 8]);
      }
      #pragma unroll
      for (int n = 0; n < 4; ++n)
        b[n] = *reinterpret_cast<const h8*>(&WpM[((size_t)((ph * 4 + kk) * 8 + nb0 + n) * 64 + l) * 8]);
      #pragma unroll
      for (int m = 0; m < 4; ++m)
        #pragma unroll
        for (int n = 0; n < 4; ++n)
          acc[m][n] = __builtin_amdgcn_mfma_f32_16x16x32_f16(a[m], b[n], acc[m][n], 0, 0, 0);
    }
    __syncthreads();                          // all reads of lds done
    // write result back to lds with the H perm (conflict-free: 4 lk-groups -> 4 octets)
    #pragma unroll
    for (int m = 0; m < 4; ++m) {
      #pragma unroll
      for (int n = 0; n < 4; ++n) {
        int c = (nb0 + n) * 16 + lr;
        float bv = b_mlp[ph * 128 + c];
        int g = c >> 3, eo = c & 7;
        #pragma unroll
        for (int q = 0; q < 4; ++q) {
          int R = m0w + m * 16 + lk * 4 + q;
          float v = fmaxf(acc[m][n][q] + bv, 0.0f);
          lds[R * 128 + pg(R, g) * 8 + eo] = (_Float16)v;
        }
      }
    }
    __syncthreads();
  }

  // head: wave w handles rows w*32 .. w*32+31; lane owns cols 2l, 2l+1 (H perm reads)
  int c0 = 2 * l;
  float w1a = W1[c0], w1b = W1[c0 + 1];
  float b1v = b1[0];
  int gH = c0 >> 3, eo = c0 & 7;
  for (int rr = 0; rr < 32; ++rr) {
    int R = w * 32 + rr;
    long grow = row0 + R;
    h2 v = *reinterpret_cast<const h2*>(&lds[R * 128 + pg(R, gH) * 8 + eo]);
    float s = (float)v[0] * w1a + (float)v[1] * w1b;
    #pragma unroll
    for (int o = 32; o > 0; o >>= 1) s += __shfl_down(s, o);
    if (l == 0 && grow < NN) out[grow] = fmaxf(s + b1v, 0.0f);
  }
}

// ---------------- launch ----------------

extern "C" void kernel_launch(void* const* d_in, const int* in_sizes, int n_in,
                              void* d_out, int out_size, void* d_ws, size_t ws_size,
                              hipStream_t stream) {
  const float* x     = (const float*)d_in[0];
  const int*   ei    = (const int*)d_in[1];
  const float* W0    = (const float*)d_in[2];
  const float* b0    = (const float*)d_in[3];
  const float* W_tag = (const float*)d_in[4];
  const float* b_tag = (const float*)d_in[5];
  const float* W_mlp = (const float*)d_in[6];
  const float* b_mlp = (const float*)d_in[7];
  const float* W1    = (const float*)d_in[8];
  const float* b1    = (const float*)d_in[9];
  const int* row = ei;          // edge_index[0] = source
  const int* col = ei + NE;     // edge_index[1] = target

  char* p = (char*)d_ws;
  auto carve = [&](size_t bytes) { void* r = (void*)p; p += (bytes + 255) & ~(size_t)255; return r; };
  _Float16* hA   = (_Float16*)carve((size_t)NP * CC * 2);
  _Float16* hB   = (_Float16*)carve((size_t)NP * CC * 2);
  _Float16* x1   = (_Float16*)carve((size_t)NP * CC * 2);
  _Float16* x2   = (_Float16*)carve((size_t)NP * CC * 2);
  _Float16* x3   = (_Float16*)carve((size_t)NP * CC * 2);
  _Float16* WpT  = (_Float16*)carve((size_t)1024 * CC * 2);  // both TAG layers
  _Float16* WpM  = (_Float16*)carve((size_t)256 * CC * 2);   // both MLP layers (contig after WpT)
  float* dis     = (float*)carve((size_t)NP * 4);
  int*   dc      = (int*)carve((size_t)(NP + NN) * 4);       // deg | cnt (zeroed by k_zero)
  int*   deg     = dc;
  int*   cnt     = dc + NP;
  int*   rowptr  = (int*)carve((size_t)(NP + 8) * 4);
  int*   bsum    = (int*)carve(512);
  int*   bsum2   = (int*)carve(512);
  int2*  csr     = (int2*)carve((size_t)NE * 8);

  // custom zero kernel (hipMemsetAsync's fillBufferAligned measured 43µs @ 18.5 GB/s
  // for this 800KB buffer — r16 rocprof; this is ~3µs)
  k_zero<<<(DC_INT4 + 255) / 256, 256, 0, stream>>>((int4*)dc);

  k_deg<<<(NE + 255) / 256, 256, 0, stream>>>(col, deg);
  k_scan1<<<98, 1024, 0, stream>>>(deg, rowptr, bsum, dis);
  k_scan2<<<1, 128, 0, stream>>>(bsum, bsum2, rowptr);
  k_scan3<<<98, 1024, 0, stream>>>(rowptr, bsum2);
  k_fill<<<(NE + 255) / 256, 256, 0, stream>>>(row, col, dis, rowptr, cnt, csr);

  k_wconv2<<<(1280 * CC + 255) / 256, 256, 0, stream>>>(W_tag, W_mlp, WpT);

  k_lin0<<<NP * CC / 256, 256, 0, stream>>>(x, W0, b0, hA);

  const int GB = NP / 128;             // 782 gemm blocks
  const int PB = (NP / 4) * 64 / 256;  // prop blocks: 4 nodes/wave, 4 waves/block

  _Float16* hc = hA;
  _Float16* hn = hB;
  for (int g = 0; g < 2; ++g) {
    k_prop<<<PB, 256, 0, stream>>>(rowptr, csr, hc, x1);
    k_prop<<<PB, 256, 0, stream>>>(rowptr, csr, x1, x2);
    k_prop<<<PB, 256, 0, stream>>>(rowptr, csr, x2, x3);
    k_mm<4, true><<<GB, 256, 0, stream>>>(hc, x1, x2, x3, WpT + (size_t)g * 512 * CC,
                                          b_tag + (size_t)g * CC, hn);
    _Float16* tmp = hc; hc = hn; hn = tmp;
  }

  k_tail<<<GB, 256, 0, stream>>>(hc, WpM, b_mlp, W1, b1, (float*)d_out);
}

// Round 19
// 373.925 us; speedup vs baseline: 1.0065x; 1.0065x over previous
//
#include <hip/hip_runtime.h>

#define NN 100000   // real nodes
#define NP 100096   // padded to 782*128
#define NE 600000   // edges
#define CC 128      // channels

typedef __attribute__((ext_vector_type(4))) float f32x4;
typedef _Float16 h8 __attribute__((ext_vector_type(8)));
typedef _Float16 h2 __attribute__((ext_vector_type(2)));

// H-region LDS granule perm: conflict-free for BOTH the C-write pattern (4 lk-groups
// -> 4 distinct bank octets) and the A-read pattern (uniform 8 dwords/bank).
__device__ __forceinline__ int pg(int R, int g) {
  return g ^ (R & 7) ^ (((R >> 2) & 3) << 1);
}

// ---------------- zero-init (replaces hipMemsetAsync; r18: timing-neutral, kept
// because it is never slower and avoids the runtime fill path) ----------------

#define DC_INT4 ((NP + NN) / 4)   // 200096 ints -> 50024 int4s

__global__ void k_zero(int4* __restrict__ dst) {
  int i = blockIdx.x * 256 + threadIdx.x;
  if (i < DC_INT4) dst[i] = make_int4(0, 0, 0, 0);
}

// ---------------- graph preprocessing ----------------

__global__ void k_deg(const int* __restrict__ col, int* __restrict__ deg) {
  int e = blockIdx.x * 256 + threadIdx.x;
  if (e < NE) atomicAdd(&deg[col[e]], 1);
}

// scan1 also emits dis[] (needs only deg[i], already loaded)
__global__ void k_scan1(const int* __restrict__ deg, int* __restrict__ rowptr,
                        int* __restrict__ bsum, float* __restrict__ dis) {
  __shared__ int s[1024];
  int t = threadIdx.x;
  int i = blockIdx.x * 1024 + t;
  int v = (i < NN) ? deg[i] : 0;
  if (i < NN) dis[i] = (v > 0) ? rsqrtf((float)v) : 0.0f;
  s[t] = v;
  __syncthreads();
  #pragma unroll
  for (int off = 1; off < 1024; off <<= 1) {
    int tv = (t >= off) ? s[t - off] : 0;
    __syncthreads();
    s[t] += tv;
    __syncthreads();
  }
  if (i < NN) rowptr[i] = s[t] - v;           // exclusive
  if (t == 1023) bsum[blockIdx.x] = s[1023];
}

// scan2 also writes the rowptr tail (padded nodes -> empty ranges)
__global__ void k_scan2(const int* __restrict__ bsum, int* __restrict__ bsum2,
                        int* __restrict__ rowptr) {
  int t = threadIdx.x;
  if (t < NP + 8 - NN) rowptr[NN + t] = NE;   // 104 entries
  __shared__ int s[128];
  int v = (t < 98) ? bsum[t] : 0;
  s[t] = v;
  __syncthreads();
  #pragma unroll
  for (int off = 1; off < 128; off <<= 1) {
    int tv = (t >= off) ? s[t - off] : 0;
    __syncthreads();
    s[t] += tv;
    __syncthreads();
  }
  bsum2[t] = s[t] - v;                        // exclusive
}

__global__ void k_scan3(int* __restrict__ rowptr, const int* __restrict__ bsum2) {
  int i = blockIdx.x * 1024 + threadIdx.x;
  if (i < NN) rowptr[i] += bsum2[blockIdx.x];
}

// packed CSR entry: {src_node*CC, float_bits(norm_w)} -> one 8B load per edge
__global__ void k_fill(const int* __restrict__ row, const int* __restrict__ col,
                       const float* __restrict__ dis, const int* __restrict__ rowptr,
                       int* __restrict__ cnt, int2* __restrict__ csr) {
  int e = blockIdx.x * 256 + threadIdx.x;
  if (e >= NE) return;
  int c = col[e], r = row[e];
  int pos = rowptr[c] + atomicAdd(&cnt[c], 1);
  int2 v;
  v.x = r * CC;
  v.y = __float_as_int(dis[r] * dis[c]);
  csr[pos] = v;
}

// ---------------- lin0: h = relu(x @ W0 + b0), x is [N,6], out fp16 ----------------

__global__ void k_lin0(const float* __restrict__ x, const float* __restrict__ W0,
                       const float* __restrict__ b0, _Float16* __restrict__ h) {
  int idx = blockIdx.x * 256 + threadIdx.x;   // n*128 + c
  int n = idx >> 7, c = idx & 127;
  if (n >= NP) return;
  float v = 0.0f;
  if (n < NN) {
    v = b0[c];
    #pragma unroll
    for (int f = 0; f < 6; ++f) v = fmaf(x[n * 6 + f], W0[f * CC + c], v);
    v = fmaxf(v, 0.0f);
  }
  h[idx] = (_Float16)v;
}

// ---------------- W conversion (both weight sets in one launch) ----------------
// fp32 [K][128] -> fp16 MFMA-B-permuted; dst = WpT (1024 rows) || WpM (256 rows)

__global__ void k_wconv2(const float* __restrict__ srcT, const float* __restrict__ srcM,
                         _Float16* __restrict__ dst) {
  int tid0 = blockIdx.x * 256 + threadIdx.x;
  if (tid0 >= 1280 * 128) return;
  const float* src = srcT;
  int tid = tid0;
  if (tid0 >= 1024 * 128) { src = srcM; tid = tid0 - 1024 * 128; }
  int e = tid & 7, l = (tid >> 3) & 63, nb = (tid >> 9) & 7, kb = tid >> 12;
  int k = kb * 32 + (l >> 4) * 8 + e;
  int c = nb * 16 + (l & 15);
  dst[tid0] = (_Float16)src[k * 128 + c];
}

// ---------------- propagation: 4 nodes/wave, contiguous CSR, 8-deep gather MLP ----
// (round-10 variant: best measured; at the ~4.7-5.1 TB/s random-gather fabric
// ceiling, invariant across 3 structural variants r3/r10/r11 — do not touch)

__global__ __launch_bounds__(256) void k_prop(const int* __restrict__ rowptr,
                                              const int2* __restrict__ csr,
                                              const _Float16* __restrict__ xin,
                                              _Float16* __restrict__ xout) {
  int gid = blockIdx.x * 256 + threadIdx.x;
  int wv = gid >> 6;             // wave -> nodes 4*wv .. 4*wv+3
  int lane = gid & 63;
  int n0 = wv * 4;
  if (n0 >= NP) return;
  int b0 = rowptr[n0], b1 = rowptr[n0 + 1], b2 = rowptr[n0 + 2],
      b3 = rowptr[n0 + 3], b4 = rowptr[n0 + 4];
  int e4 = b4 - b0;

  int2 ew; ew.x = 0; ew.y = 0;   // w=0 padding: contributes nothing, gathers node 0
  int gl = 0;
  if (lane < e4) {
    int pos = b0 + lane;
    ew = csr[pos];
    gl = (pos >= b1) + (pos >= b2) + (pos >= b3);
  }

  float a00 = 0, a01 = 0, a10 = 0, a11 = 0, a20 = 0, a21 = 0, a30 = 0, a31 = 0;
  int nb = e4 < 64 ? e4 : 64;
  for (int j = 0; j < nb; j += 8) {
    #pragma unroll
    for (int u = 0; u < 8; ++u) {
      int off = __shfl(ew.x, j + u);
      float w = __uint_as_float(__shfl(ew.y, j + u));
      int gg = __shfl(gl, j + u);
      h2 v = *reinterpret_cast<const h2*>(&xin[off + lane * 2]);
      float v0 = (float)v[0], v1 = (float)v[1];
      float w0 = (gg == 0) ? w : 0.0f;
      float w1 = (gg == 1) ? w : 0.0f;
      float w2 = (gg == 2) ? w : 0.0f;
      float w3 = (gg == 3) ? w : 0.0f;
      a00 += w0 * v0; a01 += w0 * v1;
      a10 += w1 * v0; a11 += w1 * v1;
      a20 += w2 * v0; a21 += w2 * v1;
      a30 += w3 * v0; a31 += w3 * v1;
    }
  }
  for (int j = 64; j < e4; ++j) {              // astronomically rare tail
    int pos = b0 + j;
    int2 e2 = csr[pos];
    float w = __uint_as_float(e2.y);
    int gg = (pos >= b1) + (pos >= b2) + (pos >= b3);
    h2 v = *reinterpret_cast<const h2*>(&xin[e2.x + lane * 2]);
    float v0 = (float)v[0], v1 = (float)v[1];
    float w0 = (gg == 0) ? w : 0.0f;
    float w1 = (gg == 1) ? w : 0.0f;
    float w2 = (gg == 2) ? w : 0.0f;
    float w3 = (gg == 3) ? w : 0.0f;
    a00 += w0 * v0; a01 += w0 * v1;
    a10 += w1 * v0; a11 += w1 * v1;
    a20 += w2 * v0; a21 += w2 * v1;
    a30 += w3 * v0; a31 += w3 * v1;
  }

  h2 o;
  o[0] = (_Float16)a00; o[1] = (_Float16)a01;
  *reinterpret_cast<h2*>(&xout[(size_t)(n0 + 0) * CC + lane * 2]) = o;
  o[0] = (_Float16)a10; o[1] = (_Float16)a11;
  *reinterpret_cast<h2*>(&xout[(size_t)(n0 + 1) * CC + lane * 2]) = o;
  o[0] = (_Float16)a20; o[1] = (_Float16)a21;
  *reinterpret_cast<h2*>(&xout[(size_t)(n0 + 2) * CC + lane * 2]) = o;
  o[0] = (_Float16)a30; o[1] = (_Float16)a31;
  *reinterpret_cast<h2*>(&xout[(size_t)(n0 + 3) * CC + lane * 2]) = o;
}

// ---------------- MFMA GEMM: Y = relu?(cat(X0..X3) @ Wp + bias) ----------------
// BK=64 half-tile double-buffer: 2 x 16 KB LDS (32 KB total -> ~5 blocks/CU vs 2
// at r18's 64 KB). 2*KB chunks of K=64; counted vmcnt(4) keeps the next chunk's 4
// global_load_lds in flight across the barrier (never drain to 0 mid-loop).

template<int KB, bool BR>
__global__ __launch_bounds__(256) void k_mm(const _Float16* __restrict__ X0,
                                            const _Float16* __restrict__ X1,
                                            const _Float16* __restrict__ X2,
                                            const _Float16* __restrict__ X3,
                                            const _Float16* __restrict__ Wp,
                                            const float* __restrict__ bias,
                                            _Float16* __restrict__ Y) {
  __shared__ _Float16 lds[2][128 * 64];       // 2 x 16 KB
  int t = threadIdx.x;
  int w = t >> 6, l = t & 63;
  int lr = l & 15, lk = l >> 4;
  int m0w = (w & 1) * 64;
  int nb0 = (w >> 1) * 4;
  long row0 = (long)blockIdx.x * 128;
  const _Float16* Xs[4] = {X0, X1, X2, X3};

  // stage one 128x64 half-tile (chunk c: buffer Xs[c>>1], cols (c&1)*64..+63)
  auto stage = [&](int buf, const _Float16* __restrict__ xb, int half) {
    #pragma unroll
    for (int i = 0; i < 4; ++i) {
      int li = i * 256 + t;                   // 16B-granule index 0..1023
      int r = li >> 3, ck = li & 7;           // 8 granules per 64-col row
      int cs = ck ^ (r & 7);
      const _Float16* src = xb + (size_t)(row0 + r) * CC + half * 64 + cs * 8;
      _Float16* dst = &lds[buf][i * 2048 + (t & 192) * 8];  // wave-uniform base
      __builtin_amdgcn_global_load_lds((const __attribute__((address_space(1))) void*)src,
                                       (__attribute__((address_space(3))) void*)dst,
                                       16, 0, 0);
    }
  };

  f32x4 acc[4][4];
  #pragma unroll
  for (int m = 0; m < 4; ++m)
    #pragma unroll
    for (int n = 0; n < 4; ++n) acc[m][n] = (f32x4){0.f, 0.f, 0.f, 0.f};

  stage(0, Xs[0], 0);
  #pragma unroll
  for (int c = 0; c < KB * 2; ++c) {
    if (c + 1 < KB * 2) {
      stage((c + 1) & 1, Xs[(c + 1) >> 1], (c + 1) & 1);
      asm volatile("s_waitcnt vmcnt(4)" ::: "memory");   // chunk c resident; c+1 in flight
    } else {
      asm volatile("s_waitcnt vmcnt(0)" ::: "memory");
    }
    __builtin_amdgcn_sched_barrier(0);
    __builtin_amdgcn_s_barrier();
    const _Float16* __restrict__ lb = lds[c & 1];

    #pragma unroll
    for (int kk = 0; kk < 2; ++kk) {          // K=64 chunk = 2 x K32 steps
      int kb = c * 2 + kk;                    // global 32-col K block
      h8 a[4], b[4];
      #pragma unroll
      for (int m = 0; m < 4; ++m) {
        int R = m0w + m * 16 + lr;
        a[m] = *reinterpret_cast<const h8*>(&lb[R * 64 + (((kk * 4 + lk) ^ (R & 7)) << 3)]);
      }
      #pragma unroll
      for (int n = 0; n < 4; ++n)
        b[n] = *reinterpret_cast<const h8*>(&Wp[((size_t)(kb * 8 + nb0 + n) * 64 + l) * 8]);
      #pragma unroll
      for (int m = 0; m < 4; ++m)
        #pragma unroll
        for (int n = 0; n < 4; ++n)
          acc[m][n] = __builtin_amdgcn_mfma_f32_16x16x32_f16(a[m], b[n], acc[m][n], 0, 0, 0);
    }
    __builtin_amdgcn_s_barrier();             // reads done before next stage overwrites
  }

  // C/D layout: col = lane&15, row = (lane>>4)*4 + reg
  int r0 = m0w + lk * 4;
  long rb = row0 + r0;
  #pragma unroll
  for (int m = 0; m < 4; ++m) {
    #pragma unroll
    for (int n = 0; n < 4; ++n) {
      int c = (nb0 + n) * 16 + lr;
      float bv = BR ? bias[c] : 0.0f;
      #pragma unroll
      for (int q = 0; q < 4; ++q) {
        float v = acc[m][n][q] + bv;
        if (BR) v = fmaxf(v, 0.0f);
        Y[(rb + m * 16 + q) * CC + c] = (_Float16)v;
      }
    }
  }
}

// ---------------- fused tail: h1=relu(X@M0+b0'); h2=relu(h1@M1+b1'); out=relu(h2@W1+b1) ----
// one 128-row block; h1/h2 live in LDS with the pg() perm (conflict-free write AND read).

__global__ __launch_bounds__(256) void k_tail(const _Float16* __restrict__ X,
                                              const _Float16* __restrict__ WpM,
                                              const float* __restrict__ b_mlp,
                                              const float* __restrict__ W1,
                                              const float* __restrict__ b1,
                                              float* __restrict__ out) {
  __shared__ _Float16 lds[128 * 128];         // 32 KB
  int t = threadIdx.x;
  int w = t >> 6, l = t & 63;
  int lr = l & 15, lk = l >> 4;
  int m0w = (w & 1) * 64;
  int nb0 = (w >> 1) * 4;
  long row0 = (long)blockIdx.x * 128;

  // stage X tile (pre-swizzled source -> linear LDS; X-read perm = g ^ (r&7))
  #pragma unroll
  for (int i = 0; i < 8; ++i) {
    int li = i * 256 + t;
    int r = li >> 4, ck = li & 15;
    int cs = ck ^ (r & 7);
    const _Float16* src = X + (size_t)(row0 + r) * CC + cs * 8;
    _Float16* dst = &lds[i * 2048 + (t & 192) * 8];
    __builtin_amdgcn_global_load_lds((const __attribute__((address_space(1))) void*)src,
                                     (__attribute__((address_space(3))) void*)dst,
                                     16, 0, 0);
  }
  __syncthreads();

  f32x4 acc[4][4];
  #pragma unroll
  for (int ph = 0; ph < 2; ++ph) {
    #pragma unroll
    for (int m = 0; m < 4; ++m)
      #pragma unroll
      for (int n = 0; n < 4; ++n) acc[m][n] = (f32x4){0.f, 0.f, 0.f, 0.f};
    #pragma unroll
    for (int kk = 0; kk < 4; ++kk) {
      h8 a[4], b[4];
      #pragma unroll
      for (int m = 0; m < 4; ++m) {
        int R = m0w + m * 16 + lr;
        int g = kk * 4 + lk;
        int gp = (ph == 0) ? (g ^ (R & 7)) : pg(R, g);   // X-perm pass 0, H-perm pass 1
        a[m] = *reinterpret_cast<const h8*>(&lds[R * 128 + gp * 8]);
      }
      #pragma unroll
      for (int n = 0; n < 4; ++n)
        b[n] = *reinterpret_cast<const h8*>(&WpM[((size_t)((ph * 4 + kk) * 8 + nb0 + n) * 64 + l) * 8]);
      #pragma unroll
      for (int m = 0; m < 4; ++m)
        #pragma unroll
        for (int n = 0; n < 4; ++n)
          acc[m][n] = __builtin_amdgcn_mfma_f32_16x16x32_f16(a[m], b[n], acc[m][n], 0, 0, 0);
    }
    __syncthreads();                          // all reads of lds done
    // write result back to lds with the H perm (conflict-free: 4 lk-groups -> 4 octets)
    #pragma unroll
    for (int m = 0; m < 4; ++m) {
      #pragma unroll
      for (int n = 0; n < 4; ++n) {
        int c = (nb0 + n) * 16 + lr;
        float bv = b_mlp[ph * 128 + c];
        int g = c >> 3, eo = c & 7;
        #pragma unroll
        for (int q = 0; q < 4; ++q) {
          int R = m0w + m * 16 + lk * 4 + q;
          float v = fmaxf(acc[m][n][q] + bv, 0.0f);
          lds[R * 128 + pg(R, g) * 8 + eo] = (_Float16)v;
        }
      }
    }
    __syncthreads();
  }

  // head: wave w handles rows w*32 .. w*32+31; lane owns cols 2l, 2l+1 (H perm reads)
  int c0 = 2 * l;
  float w1a = W1[c0], w1b = W1[c0 + 1];
  float b1v = b1[0];
  int gH = c0 >> 3, eo = c0 & 7;
  for (int rr = 0; rr < 32; ++rr) {
    int R = w * 32 + rr;
    long grow = row0 + R;
    h2 v = *reinterpret_cast<const h2*>(&lds[R * 128 + pg(R, gH) * 8 + eo]);
    float s = (float)v[0] * w1a + (float)v[1] * w1b;
    #pragma unroll
    for (int o = 32; o > 0; o >>= 1) s += __shfl_down(s, o);
    if (l == 0 && grow < NN) out[grow] = fmaxf(s + b1v, 0.0f);
  }
}

// ---------------- launch ----------------

extern "C" void kernel_launch(void* const* d_in, const int* in_sizes, int n_in,
                              void* d_out, int out_size, void* d_ws, size_t ws_size,
                              hipStream_t stream) {
  const float* x     = (const float*)d_in[0];
  const int*   ei    = (const int*)d_in[1];
  const float* W0    = (const float*)d_in[2];
  const float* b0    = (const float*)d_in[3];
  const float* W_tag = (const float*)d_in[4];
  const float* b_tag = (const float*)d_in[5];
  const float* W_mlp = (const float*)d_in[6];
  const float* b_mlp = (const float*)d_in[7];
  const float* W1    = (const float*)d_in[8];
  const float* b1    = (const float*)d_in[9];
  const int* row = ei;          // edge_index[0] = source
  const int* col = ei + NE;     // edge_index[1] = target

  char* p = (char*)d_ws;
  auto carve = [&](size_t bytes) { void* r = (void*)p; p += (bytes + 255) & ~(size_t)255; return r; };
  _Float16* hA   = (_Float16*)carve((size_t)NP * CC * 2);
  _Float16* hB   = (_Float16*)carve((size_t)NP * CC * 2);
  _Float16* x1   = (_Float16*)carve((size_t)NP * CC * 2);
  _Float16* x2   = (_Float16*)carve((size_t)NP * CC * 2);
  _Float16* x3   = (_Float16*)carve((size_t)NP * CC * 2);
  _Float16* WpT  = (_Float16*)carve((size_t)1024 * CC * 2);  // both TAG layers
  _Float16* WpM  = (_Float16*)carve((size_t)256 * CC * 2);   // both MLP layers (contig after WpT)
  float* dis     = (float*)carve((size_t)NP * 4);
  int*   dc      = (int*)carve((size_t)(NP + NN) * 4);       // deg | cnt (zeroed by k_zero)
  int*   deg     = dc;
  int*   cnt     = dc + NP;
  int*   rowptr  = (int*)carve((size_t)(NP + 8) * 4);
  int*   bsum    = (int*)carve(512);
  int*   bsum2   = (int*)carve(512);
  int2*  csr     = (int2*)carve((size_t)NE * 8);

  k_zero<<<(DC_INT4 + 255) / 256, 256, 0, stream>>>((int4*)dc);

  k_deg<<<(NE + 255) / 256, 256, 0, stream>>>(col, deg);
  k_scan1<<<98, 1024, 0, stream>>>(deg, rowptr, bsum, dis);
  k_scan2<<<1, 128, 0, stream>>>(bsum, bsum2, rowptr);
  k_scan3<<<98, 1024, 0, stream>>>(rowptr, bsum2);
  k_fill<<<(NE + 255) / 256, 256, 0, stream>>>(row, col, dis, rowptr, cnt, csr);

  k_wconv2<<<(1280 * CC + 255) / 256, 256, 0, stream>>>(W_tag, W_mlp, WpT);

  k_lin0<<<NP * CC / 256, 256, 0, stream>>>(x, W0, b0, hA);

  const int GB = NP / 128;             // 782 gemm blocks
  const int PB = (NP / 4) * 64 / 256;  // prop blocks: 4 nodes/wave, 4 waves/block

  _Float16* hc = hA;
  _Float16* hn = hB;
  for (int g = 0; g < 2; ++g) {
    k_prop<<<PB, 256, 0, stream>>>(rowptr, csr, hc, x1);
    k_prop<<<PB, 256, 0, stream>>>(rowptr, csr, x1, x2);
    k_prop<<<PB, 256, 0, stream>>>(rowptr, csr, x2, x3);
    k_mm<4, true><<<GB, 256, 0, stream>>>(hc, x1, x2, x3, WpT + (size_t)g * 512 * CC,
                                          b_tag + (size_t)g * CC, hn);
    _Float16* tmp = hc; hc = hn; hn = tmp;
  }

  k_tail<<<GB, 256, 0, stream>>>(hc, WpM, b_mlp, W1, b1, (float*)d_out);
}

// Round 20
// 352.568 us; speedup vs baseline: 1.0674x; 1.0606x over previous
//
#include <hip/hip_runtime.h>

#define NN 100000   // real nodes
#define NP 100096   // padded to 782*128
#define NE 600000   // edges
#define CC 128      // channels

typedef __attribute__((ext_vector_type(4))) float f32x4;
typedef _Float16 h8 __attribute__((ext_vector_type(8)));
typedef _Float16 h2 __attribute__((ext_vector_type(2)));

// H-region LDS granule perm (bijective per row; conflicts measured negligible either way)
__device__ __forceinline__ int pg(int R, int g) {
  return g ^ (R & 7) ^ (((R >> 2) & 3) << 1);
}

#define DC_INT4 ((NP + NN) / 4)

__global__ void k_zero(int4* __restrict__ dst) {
  int i = blockIdx.x * 256 + threadIdx.x;
  if (i < DC_INT4) dst[i] = make_int4(0, 0, 0, 0);
}

// ---------------- graph preprocessing ----------------

__global__ void k_deg(const int* __restrict__ col, int* __restrict__ deg) {
  int e = blockIdx.x * 256 + threadIdx.x;
  if (e < NE) atomicAdd(&deg[col[e]], 1);
}

__global__ void k_scan1(const int* __restrict__ deg, int* __restrict__ rowptr,
                        int* __restrict__ bsum, float* __restrict__ dis) {
  __shared__ int s[1024];
  int t = threadIdx.x;
  int i = blockIdx.x * 1024 + t;
  int v = (i < NN) ? deg[i] : 0;
  if (i < NN) dis[i] = (v > 0) ? rsqrtf((float)v) : 0.0f;
  s[t] = v;
  __syncthreads();
  #pragma unroll
  for (int off = 1; off < 1024; off <<= 1) {
    int tv = (t >= off) ? s[t - off] : 0;
    __syncthreads();
    s[t] += tv;
    __syncthreads();
  }
  if (i < NN) rowptr[i] = s[t] - v;           // exclusive
  if (t == 1023) bsum[blockIdx.x] = s[1023];
}

__global__ void k_scan2(const int* __restrict__ bsum, int* __restrict__ bsum2,
                        int* __restrict__ rowptr) {
  int t = threadIdx.x;
  if (t < NP + 8 - NN) rowptr[NN + t] = NE;   // 104 entries
  __shared__ int s[128];
  int v = (t < 98) ? bsum[t] : 0;
  s[t] = v;
  __syncthreads();
  #pragma unroll
  for (int off = 1; off < 128; off <<= 1) {
    int tv = (t >= off) ? s[t - off] : 0;
    __syncthreads();
    s[t] += tv;
    __syncthreads();
  }
  bsum2[t] = s[t] - v;                        // exclusive
}

__global__ void k_scan3(int* __restrict__ rowptr, const int* __restrict__ bsum2) {
  int i = blockIdx.x * 1024 + threadIdx.x;
  if (i < NN) rowptr[i] += bsum2[blockIdx.x];
}

__global__ void k_fill(const int* __restrict__ row, const int* __restrict__ col,
                       const float* __restrict__ dis, const int* __restrict__ rowptr,
                       int* __restrict__ cnt, int2* __restrict__ csr) {
  int e = blockIdx.x * 256 + threadIdx.x;
  if (e >= NE) return;
  int c = col[e], r = row[e];
  int pos = rowptr[c] + atomicAdd(&cnt[c], 1);
  int2 v;
  v.x = r * CC;
  v.y = __float_as_int(dis[r] * dis[c]);
  csr[pos] = v;
}

// ---------------- lin0 ----------------

__global__ void k_lin0(const float* __restrict__ x, const float* __restrict__ W0,
                       const float* __restrict__ b0, _Float16* __restrict__ h) {
  int idx = blockIdx.x * 256 + threadIdx.x;   // n*128 + c
  int n = idx >> 7, c = idx & 127;
  if (n >= NP) return;
  float v = 0.0f;
  if (n < NN) {
    v = b0[c];
    #pragma unroll
    for (int f = 0; f < 6; ++f) v = fmaf(x[n * 6 + f], W0[f * CC + c], v);
    v = fmaxf(v, 0.0f);
  }
  h[idx] = (_Float16)v;
}

// ---------------- W conversion ----------------

__global__ void k_wconv2(const float* __restrict__ srcT, const float* __restrict__ srcM,
                         _Float16* __restrict__ dst) {
  int tid0 = blockIdx.x * 256 + threadIdx.x;
  if (tid0 >= 1280 * 128) return;
  const float* src = srcT;
  int tid = tid0;
  if (tid0 >= 1024 * 128) { src = srcM; tid = tid0 - 1024 * 128; }
  int e = tid & 7, l = (tid >> 3) & 63, nb = (tid >> 9) & 7, kb = tid >> 12;
  int k = kb * 32 + (l >> 4) * 8 + e;
  int c = nb * 16 + (l & 15);
  dst[tid0] = (_Float16)src[k * 128 + c];
}

// ---------------- propagation (r10 variant; at random-gather fabric ceiling) ----

__global__ __launch_bounds__(256) void k_prop(const int* __restrict__ rowptr,
                                              const int2* __restrict__ csr,
                                              const _Float16* __restrict__ xin,
                                              _Float16* __restrict__ xout) {
  int gid = blockIdx.x * 256 + threadIdx.x;
  int wv = gid >> 6;
  int lane = gid & 63;
  int n0 = wv * 4;
  if (n0 >= NP) return;
  int b0 = rowptr[n0], b1 = rowptr[n0 + 1], b2 = rowptr[n0 + 2],
      b3 = rowptr[n0 + 3], b4 = rowptr[n0 + 4];
  int e4 = b4 - b0;

  int2 ew; ew.x = 0; ew.y = 0;
  int gl = 0;
  if (lane < e4) {
    int pos = b0 + lane;
    ew = csr[pos];
    gl = (pos >= b1) + (pos >= b2) + (pos >= b3);
  }

  float a00 = 0, a01 = 0, a10 = 0, a11 = 0, a20 = 0, a21 = 0, a30 = 0, a31 = 0;
  int nb = e4 < 64 ? e4 : 64;
  for (int j = 0; j < nb; j += 8) {
    #pragma unroll
    for (int u = 0; u < 8; ++u) {
      int off = __shfl(ew.x, j + u);
      float w = __uint_as_float(__shfl(ew.y, j + u));
      int gg = __shfl(gl, j + u);
      h2 v = *reinterpret_cast<const h2*>(&xin[off + lane * 2]);
      float v0 = (float)v[0], v1 = (float)v[1];
      float w0 = (gg == 0) ? w : 0.0f;
      float w1 = (gg == 1) ? w : 0.0f;
      float w2 = (gg == 2) ? w : 0.0f;
      float w3 = (gg == 3) ? w : 0.0f;
      a00 += w0 * v0; a01 += w0 * v1;
      a10 += w1 * v0; a11 += w1 * v1;
      a20 += w2 * v0; a21 += w2 * v1;
      a30 += w3 * v0; a31 += w3 * v1;
    }
  }
  for (int j = 64; j < e4; ++j) {
    int pos = b0 + j;
    int2 e2 = csr[pos];
    float w = __uint_as_float(e2.y);
    int gg = (pos >= b1) + (pos >= b2) + (pos >= b3);
    h2 v = *reinterpret_cast<const h2*>(&xin[e2.x + lane * 2]);
    float v0 = (float)v[0], v1 = (float)v[1];
    float w0 = (gg == 0) ? w : 0.0f;
    float w1 = (gg == 1) ? w : 0.0f;
    float w2 = (gg == 2) ? w : 0.0f;
    float w3 = (gg == 3) ? w : 0.0f;
    a00 += w0 * v0; a01 += w0 * v1;
    a10 += w1 * v0; a11 += w1 * v1;
    a20 += w2 * v0; a21 += w2 * v1;
    a30 += w3 * v0; a31 += w3 * v1;
  }

  h2 o;
  o[0] = (_Float16)a00; o[1] = (_Float16)a01;
  *reinterpret_cast<h2*>(&xout[(size_t)(n0 + 0) * CC + lane * 2]) = o;
  o[0] = (_Float16)a10; o[1] = (_Float16)a11;
  *reinterpret_cast<h2*>(&xout[(size_t)(n0 + 1) * CC + lane * 2]) = o;
  o[0] = (_Float16)a20; o[1] = (_Float16)a21;
  *reinterpret_cast<h2*>(&xout[(size_t)(n0 + 2) * CC + lane * 2]) = o;
  o[0] = (_Float16)a30; o[1] = (_Float16)a31;
  *reinterpret_cast<h2*>(&xout[(size_t)(n0 + 3) * CC + lane * 2]) = o;
}

// ---------------- MFMA GEMM: M=64 tile (1564 blocks -> ~6 blocks/CU; r19's 782
// blocks = 3/CU was the occupancy limiter, not LDS). BK=64 chunks, dbuf 2x8KB,
// counted vmcnt(2). Wave w: rows (w&1)*32, cols (w>>1)*64.

template<int KB, bool BR>
__global__ __launch_bounds__(256) void k_mm(const _Float16* __restrict__ X0,
                                            const _Float16* __restrict__ X1,
                                            const _Float16* __restrict__ X2,
                                            const _Float16* __restrict__ X3,
                                            const _Float16* __restrict__ Wp,
                                            const float* __restrict__ bias,
                                            _Float16* __restrict__ Y) {
  __shared__ _Float16 lds[2][64 * 64];        // 2 x 8 KB
  int t = threadIdx.x;
  int w = t >> 6, l = t & 63;
  int lr = l & 15, lk = l >> 4;
  int m0w = (w & 1) * 32;
  int nb0 = (w >> 1) * 4;
  long row0 = (long)blockIdx.x * 64;
  const _Float16* Xs[4] = {X0, X1, X2, X3};

  // stage one 64x64 half-tile (chunk c: buffer Xs[c>>1], cols (c&1)*64..+63)
  auto stage = [&](int buf, const _Float16* __restrict__ xb, int half) {
    #pragma unroll
    for (int i = 0; i < 2; ++i) {
      int li = i * 256 + t;                   // 16B-granule index 0..511
      int r = li >> 3, ck = li & 7;           // 8 granules per 64-col row
      int cs = ck ^ (r & 7);
      const _Float16* src = xb + (size_t)(row0 + r) * CC + half * 64 + cs * 8;
      _Float16* dst = &lds[buf][i * 2048 + (t & 192) * 8];  // wave-uniform base
      __builtin_amdgcn_global_load_lds((const __attribute__((address_space(1))) void*)src,
                                       (__attribute__((address_space(3))) void*)dst,
                                       16, 0, 0);
    }
  };

  f32x4 acc[2][4];
  #pragma unroll
  for (int m = 0; m < 2; ++m)
    #pragma unroll
    for (int n = 0; n < 4; ++n) acc[m][n] = (f32x4){0.f, 0.f, 0.f, 0.f};

  stage(0, Xs[0], 0);
  #pragma unroll
  for (int c = 0; c < KB * 2; ++c) {
    if (c + 1 < KB * 2) {
      stage((c + 1) & 1, Xs[(c + 1) >> 1], (c + 1) & 1);
      asm volatile("s_waitcnt vmcnt(2)" ::: "memory");   // chunk c resident; c+1 in flight
    } else {
      asm volatile("s_waitcnt vmcnt(0)" ::: "memory");
    }
    __builtin_amdgcn_sched_barrier(0);
    __builtin_amdgcn_s_barrier();
    const _Float16* __restrict__ lb = lds[c & 1];

    #pragma unroll
    for (int kk = 0; kk < 2; ++kk) {          // K=64 chunk = 2 x K32 steps
      int kb = c * 2 + kk;
      h8 a[2], b[4];
      #pragma unroll
      for (int m = 0; m < 2; ++m) {
        int R = m0w + m * 16 + lr;
        a[m] = *reinterpret_cast<const h8*>(&lb[R * 64 + (((kk * 4 + lk) ^ (R & 7)) << 3)]);
      }
      #pragma unroll
      for (int n = 0; n < 4; ++n)
        b[n] = *reinterpret_cast<const h8*>(&Wp[((size_t)(kb * 8 + nb0 + n) * 64 + l) * 8]);
      #pragma unroll
      for (int m = 0; m < 2; ++m)
        #pragma unroll
        for (int n = 0; n < 4; ++n)
          acc[m][n] = __builtin_amdgcn_mfma_f32_16x16x32_f16(a[m], b[n], acc[m][n], 0, 0, 0);
    }
    __builtin_amdgcn_s_barrier();
  }

  // C/D layout: col = lane&15, row = (lane>>4)*4 + reg
  int r0 = m0w + lk * 4;
  long rb = row0 + r0;
  #pragma unroll
  for (int m = 0; m < 2; ++m) {
    #pragma unroll
    for (int n = 0; n < 4; ++n) {
      int c = (nb0 + n) * 16 + lr;
      float bv = BR ? bias[c] : 0.0f;
      #pragma unroll
      for (int q = 0; q < 4; ++q) {
        float v = acc[m][n][q] + bv;
        if (BR) v = fmaxf(v, 0.0f);
        Y[(rb + m * 16 + q) * CC + c] = (_Float16)v;
      }
    }
  }
}

// ---------------- fused tail: wave-parallel head (8 b128 + 32 shfl vs r19's
// 32 scalar reads + 192 shfl serial loop) ----------------

__global__ __launch_bounds__(256) void k_tail(const _Float16* __restrict__ X,
                                              const _Float16* __restrict__ WpM,
                                              const float* __restrict__ b_mlp,
                                              const float* __restrict__ W1,
                                              const float* __restrict__ b1,
                                              float* __restrict__ out) {
  __shared__ _Float16 lds[128 * 128];         // 32 KB
  int t = threadIdx.x;
  int w = t >> 6, l = t & 63;
  int lr = l & 15, lk = l >> 4;
  int m0w = (w & 1) * 64;
  int nb0 = (w >> 1) * 4;
  long row0 = (long)blockIdx.x * 128;

  #pragma unroll
  for (int i = 0; i < 8; ++i) {
    int li = i * 256 + t;
    int r = li >> 4, ck = li & 15;
    int cs = ck ^ (r & 7);
    const _Float16* src = X + (size_t)(row0 + r) * CC + cs * 8;
    _Float16* dst = &lds[i * 2048 + (t & 192) * 8];
    __builtin_amdgcn_global_load_lds((const __attribute__((address_space(1))) void*)src,
                                     (__attribute__((address_space(3))) void*)dst,
                                     16, 0, 0);
  }
  __syncthreads();

  f32x4 acc[4][4];
  #pragma unroll
  for (int ph = 0; ph < 2; ++ph) {
    #pragma unroll
    for (int m = 0; m < 4; ++m)
      #pragma unroll
      for (int n = 0; n < 4; ++n) acc[m][n] = (f32x4){0.f, 0.f, 0.f, 0.f};
    #pragma unroll
    for (int kk = 0; kk < 4; ++kk) {
      h8 a[4], b[4];
      #pragma unroll
      for (int m = 0; m < 4; ++m) {
        int R = m0w + m * 16 + lr;
        int g = kk * 4 + lk;
        int gp = (ph == 0) ? (g ^ (R & 7)) : pg(R, g);
        a[m] = *reinterpret_cast<const h8*>(&lds[R * 128 + gp * 8]);
      }
      #pragma unroll
      for (int n = 0; n < 4; ++n)
        b[n] = *reinterpret_cast<const h8*>(&WpM[((size_t)((ph * 4 + kk) * 8 + nb0 + n) * 64 + l) * 8]);
      #pragma unroll
      for (int m = 0; m < 4; ++m)
        #pragma unroll
        for (int n = 0; n < 4; ++n)
          acc[m][n] = __builtin_amdgcn_mfma_f32_16x16x32_f16(a[m], b[n], acc[m][n], 0, 0, 0);
    }
    __syncthreads();
    #pragma unroll
    for (int m = 0; m < 4; ++m) {
      #pragma unroll
      for (int n = 0; n < 4; ++n) {
        int c = (nb0 + n) * 16 + lr;
        float bv = b_mlp[ph * 128 + c];
        int g = c >> 3, eo = c & 7;
        #pragma unroll
        for (int q = 0; q < 4; ++q) {
          int R = m0w + m * 16 + lk * 4 + q;
          float v = fmaxf(acc[m][n][q] + bv, 0.0f);
          lds[R * 128 + pg(R, g) * 8 + eo] = (_Float16)v;
        }
      }
    }
    __syncthreads();
  }

  // head (wave-parallel): lane l -> row w*32 + ps*4 + (l>>4), granule gH = l&15.
  // one ds_read_b128 + 8 FMA per pass; 4-level shfl_xor reduce over the 16 lanes
  // sharing a row; lane with (l&15)==0 writes.
  int gH = l & 15;
  float w1s[8];
  #pragma unroll
  for (int q = 0; q < 8; ++q) w1s[q] = W1[gH * 8 + q];
  float b1v = b1[0];
  #pragma unroll
  for (int ps = 0; ps < 8; ++ps) {
    int R = w * 32 + ps * 4 + (l >> 4);
    h8 hv = *reinterpret_cast<const h8*>(&lds[R * 128 + pg(R, gH) * 8]);
    float s = 0.0f;
    #pragma unroll
    for (int q = 0; q < 8; ++q) s = fmaf((float)hv[q], w1s[q], s);
    s += __shfl_xor(s, 1);
    s += __shfl_xor(s, 2);
    s += __shfl_xor(s, 4);
    s += __shfl_xor(s, 8);
    long grow = row0 + R;
    if (gH == 0 && grow < NN) out[grow] = fmaxf(s + b1v, 0.0f);
  }
}

// ---------------- launch ----------------

extern "C" void kernel_launch(void* const* d_in, const int* in_sizes, int n_in,
                              void* d_out, int out_size, void* d_ws, size_t ws_size,
                              hipStream_t stream) {
  const float* x     = (const float*)d_in[0];
  const int*   ei    = (const int*)d_in[1];
  const float* W0    = (const float*)d_in[2];
  const float* b0    = (const float*)d_in[3];
  const float* W_tag = (const float*)d_in[4];
  const float* b_tag = (const float*)d_in[5];
  const float* W_mlp = (const float*)d_in[6];
  const float* b_mlp = (const float*)d_in[7];
  const float* W1    = (const float*)d_in[8];
  const float* b1    = (const float*)d_in[9];
  const int* row = ei;          // edge_index[0] = source
  const int* col = ei + NE;     // edge_index[1] = target

  char* p = (char*)d_ws;
  auto carve = [&](size_t bytes) { void* r = (void*)p; p += (bytes + 255) & ~(size_t)255; return r; };
  _Float16* hA   = (_Float16*)carve((size_t)NP * CC * 2);
  _Float16* hB   = (_Float16*)carve((size_t)NP * CC * 2);
  _Float16* x1   = (_Float16*)carve((size_t)NP * CC * 2);
  _Float16* x2   = (_Float16*)carve((size_t)NP * CC * 2);
  _Float16* x3   = (_Float16*)carve((size_t)NP * CC * 2);
  _Float16* WpT  = (_Float16*)carve((size_t)1024 * CC * 2);
  _Float16* WpM  = (_Float16*)carve((size_t)256 * CC * 2);
  float* dis     = (float*)carve((size_t)NP * 4);
  int*   dc      = (int*)carve((size_t)(NP + NN) * 4);
  int*   deg     = dc;
  int*   cnt     = dc + NP;
  int*   rowptr  = (int*)carve((size_t)(NP + 8) * 4);
  int*   bsum    = (int*)carve(512);
  int*   bsum2   = (int*)carve(512);
  int2*  csr     = (int2*)carve((size_t)NE * 8);

  k_zero<<<(DC_INT4 + 255) / 256, 256, 0, stream>>>((int4*)dc);

  k_deg<<<(NE + 255) / 256, 256, 0, stream>>>(col, deg);
  k_scan1<<<98, 1024, 0, stream>>>(deg, rowptr, bsum, dis);
  k_scan2<<<1, 128, 0, stream>>>(bsum, bsum2, rowptr);
  k_scan3<<<98, 1024, 0, stream>>>(rowptr, bsum2);
  k_fill<<<(NE + 255) / 256, 256, 0, stream>>>(row, col, dis, rowptr, cnt, csr);

  k_wconv2<<<(1280 * CC + 255) / 256, 256, 0, stream>>>(W_tag, W_mlp, WpT);

  k_lin0<<<NP * CC / 256, 256, 0, stream>>>(x, W0, b0, hA);

  const int GB64 = NP / 64;            // 1564 gemm blocks (M=64 tile)
  const int GB   = NP / 128;           // 782 tail blocks
  const int PB   = (NP / 4) * 64 / 256;

  _Float16* hc = hA;
  _Float16* hn = hB;
  for (int g = 0; g < 2; ++g) {
    k_prop<<<PB, 256, 0, stream>>>(rowptr, csr, hc, x1);
    k_prop<<<PB, 256, 0, stream>>>(rowptr, csr, x1, x2);
    k_prop<<<PB, 256, 0, stream>>>(rowptr, csr, x2, x3);
    k_mm<4, true><<<GB64, 256, 0, stream>>>(hc, x1, x2, x3, WpT + (size_t)g * 512 * CC,
                                            b_tag + (size_t)g * CC, hn);
    _Float16* tmp = hc; hc = hn; hn = tmp;
  }

  k_tail<<<GB, 256, 0, stream>>>(hc, WpM, b_mlp, W1, b1, (float*)d_out);
}

// Round 21
// 349.331 us; speedup vs baseline: 1.0773x; 1.0093x over previous
//
#include <hip/hip_runtime.h>

#define NN 100000   // real nodes
#define NP 100096   // padded to 782*128
#define NE 600000   // edges
#define CC 128      // channels

typedef __attribute__((ext_vector_type(4))) float f32x4;
typedef _Float16 h8 __attribute__((ext_vector_type(8)));
typedef _Float16 h2 __attribute__((ext_vector_type(2)));

// H-region LDS granule perm (bijective per row)
__device__ __forceinline__ int pg(int R, int g) {
  return g ^ (R & 7) ^ (((R >> 2) & 3) << 1);
}

#define DC_INT4 ((NP + NN) / 4)

__global__ void k_zero(int4* __restrict__ dst) {
  int i = blockIdx.x * 256 + threadIdx.x;
  if (i < DC_INT4) dst[i] = make_int4(0, 0, 0, 0);
}

// ---------------- graph preprocessing ----------------

__global__ void k_deg(const int* __restrict__ col, int* __restrict__ deg) {
  int e = blockIdx.x * 256 + threadIdx.x;
  if (e < NE) atomicAdd(&deg[col[e]], 1);
}

__global__ void k_scan1(const int* __restrict__ deg, int* __restrict__ rowptr,
                        int* __restrict__ bsum, float* __restrict__ dis) {
  __shared__ int s[1024];
  int t = threadIdx.x;
  int i = blockIdx.x * 1024 + t;
  int v = (i < NN) ? deg[i] : 0;
  if (i < NN) dis[i] = (v > 0) ? rsqrtf((float)v) : 0.0f;
  s[t] = v;
  __syncthreads();
  #pragma unroll
  for (int off = 1; off < 1024; off <<= 1) {
    int tv = (t >= off) ? s[t - off] : 0;
    __syncthreads();
    s[t] += tv;
    __syncthreads();
  }
  if (i < NN) rowptr[i] = s[t] - v;           // exclusive
  if (t == 1023) bsum[blockIdx.x] = s[1023];
}

__global__ void k_scan2(const int* __restrict__ bsum, int* __restrict__ bsum2,
                        int* __restrict__ rowptr) {
  int t = threadIdx.x;
  if (t < NP + 8 - NN) rowptr[NN + t] = NE;   // 104 entries
  __shared__ int s[128];
  int v = (t < 98) ? bsum[t] : 0;
  s[t] = v;
  __syncthreads();
  #pragma unroll
  for (int off = 1; off < 128; off <<= 1) {
    int tv = (t >= off) ? s[t - off] : 0;
    __syncthreads();
    s[t] += tv;
    __syncthreads();
  }
  bsum2[t] = s[t] - v;                        // exclusive
}

__global__ void k_scan3(int* __restrict__ rowptr, const int* __restrict__ bsum2) {
  int i = blockIdx.x * 1024 + threadIdx.x;
  if (i < NN) rowptr[i] += bsum2[blockIdx.x];
}

__global__ void k_fill(const int* __restrict__ row, const int* __restrict__ col,
                       const float* __restrict__ dis, const int* __restrict__ rowptr,
                       int* __restrict__ cnt, int2* __restrict__ csr) {
  int e = blockIdx.x * 256 + threadIdx.x;
  if (e >= NE) return;
  int c = col[e], r = row[e];
  int pos = rowptr[c] + atomicAdd(&cnt[c], 1);
  int2 v;
  v.x = r * CC;
  v.y = __float_as_int(dis[r] * dis[c]);
  csr[pos] = v;
}

// ---------------- lin0 ----------------

__global__ void k_lin0(const float* __restrict__ x, const float* __restrict__ W0,
                       const float* __restrict__ b0, _Float16* __restrict__ h) {
  int idx = blockIdx.x * 256 + threadIdx.x;   // n*128 + c
  int n = idx >> 7, c = idx & 127;
  if (n >= NP) return;
  float v = 0.0f;
  if (n < NN) {
    v = b0[c];
    #pragma unroll
    for (int f = 0; f < 6; ++f) v = fmaf(x[n * 6 + f], W0[f * CC + c], v);
    v = fmaxf(v, 0.0f);
  }
  h[idx] = (_Float16)v;
}

// ---------------- W conversion ----------------

__global__ void k_wconv2(const float* __restrict__ srcT, const float* __restrict__ srcM,
                         _Float16* __restrict__ dst) {
  int tid0 = blockIdx.x * 256 + threadIdx.x;
  if (tid0 >= 1280 * 128) return;
  const float* src = srcT;
  int tid = tid0;
  if (tid0 >= 1024 * 128) { src = srcM; tid = tid0 - 1024 * 128; }
  int e = tid & 7, l = (tid >> 3) & 63, nb = (tid >> 9) & 7, kb = tid >> 12;
  int k = kb * 32 + (l >> 4) * 8 + e;
  int c = nb * 16 + (l & 15);
  dst[tid0] = (_Float16)src[k * 128 + c];
}

// ---------------- propagation (r10 variant; at random-gather fabric ceiling) ----

__global__ __launch_bounds__(256) void k_prop(const int* __restrict__ rowptr,
                                              const int2* __restrict__ csr,
                                              const _Float16* __restrict__ xin,
                                              _Float16* __restrict__ xout) {
  int gid = blockIdx.x * 256 + threadIdx.x;
  int wv = gid >> 6;
  int lane = gid & 63;
  int n0 = wv * 4;
  if (n0 >= NP) return;
  int b0 = rowptr[n0], b1 = rowptr[n0 + 1], b2 = rowptr[n0 + 2],
      b3 = rowptr[n0 + 3], b4 = rowptr[n0 + 4];
  int e4 = b4 - b0;

  int2 ew; ew.x = 0; ew.y = 0;
  int gl = 0;
  if (lane < e4) {
    int pos = b0 + lane;
    ew = csr[pos];
    gl = (pos >= b1) + (pos >= b2) + (pos >= b3);
  }

  float a00 = 0, a01 = 0, a10 = 0, a11 = 0, a20 = 0, a21 = 0, a30 = 0, a31 = 0;
  int nb = e4 < 64 ? e4 : 64;
  for (int j = 0; j < nb; j += 8) {
    #pragma unroll
    for (int u = 0; u < 8; ++u) {
      int off = __shfl(ew.x, j + u);
      float w = __uint_as_float(__shfl(ew.y, j + u));
      int gg = __shfl(gl, j + u);
      h2 v = *reinterpret_cast<const h2*>(&xin[off + lane * 2]);
      float v0 = (float)v[0], v1 = (float)v[1];
      float w0 = (gg == 0) ? w : 0.0f;
      float w1 = (gg == 1) ? w : 0.0f;
      float w2 = (gg == 2) ? w : 0.0f;
      float w3 = (gg == 3) ? w : 0.0f;
      a00 += w0 * v0; a01 += w0 * v1;
      a10 += w1 * v0; a11 += w1 * v1;
      a20 += w2 * v0; a21 += w2 * v1;
      a30 += w3 * v0; a31 += w3 * v1;
    }
  }
  for (int j = 64; j < e4; ++j) {
    int pos = b0 + j;
    int2 e2 = csr[pos];
    float w = __uint_as_float(e2.y);
    int gg = (pos >= b1) + (pos >= b2) + (pos >= b3);
    h2 v = *reinterpret_cast<const h2*>(&xin[e2.x + lane * 2]);
    float v0 = (float)v[0], v1 = (float)v[1];
    float w0 = (gg == 0) ? w : 0.0f;
    float w1 = (gg == 1) ? w : 0.0f;
    float w2 = (gg == 2) ? w : 0.0f;
    float w3 = (gg == 3) ? w : 0.0f;
    a00 += w0 * v0; a01 += w0 * v1;
    a10 += w1 * v0; a11 += w1 * v1;
    a20 += w2 * v0; a21 += w2 * v1;
    a30 += w3 * v0; a31 += w3 * v1;
  }

  h2 o;
  o[0] = (_Float16)a00; o[1] = (_Float16)a01;
  *reinterpret_cast<h2*>(&xout[(size_t)(n0 + 0) * CC + lane * 2]) = o;
  o[0] = (_Float16)a10; o[1] = (_Float16)a11;
  *reinterpret_cast<h2*>(&xout[(size_t)(n0 + 1) * CC + lane * 2]) = o;
  o[0] = (_Float16)a20; o[1] = (_Float16)a21;
  *reinterpret_cast<h2*>(&xout[(size_t)(n0 + 2) * CC + lane * 2]) = o;
  o[0] = (_Float16)a30; o[1] = (_Float16)a31;
  *reinterpret_cast<h2*>(&xout[(size_t)(n0 + 3) * CC + lane * 2]) = o;
}

// ---------------- MFMA GEMM: M=64 tile, BK=64 dbuf, counted vmcnt(2) (r20 form) ----

template<int KB, bool BR>
__global__ __launch_bounds__(256) void k_mm(const _Float16* __restrict__ X0,
                                            const _Float16* __restrict__ X1,
                                            const _Float16* __restrict__ X2,
                                            const _Float16* __restrict__ X3,
                                            const _Float16* __restrict__ Wp,
                                            const float* __restrict__ bias,
                                            _Float16* __restrict__ Y) {
  __shared__ _Float16 lds[2][64 * 64];        // 2 x 8 KB
  int t = threadIdx.x;
  int w = t >> 6, l = t & 63;
  int lr = l & 15, lk = l >> 4;
  int m0w = (w & 1) * 32;
  int nb0 = (w >> 1) * 4;
  long row0 = (long)blockIdx.x * 64;
  const _Float16* Xs[4] = {X0, X1, X2, X3};

  auto stage = [&](int buf, const _Float16* __restrict__ xb, int half) {
    #pragma unroll
    for (int i = 0; i < 2; ++i) {
      int li = i * 256 + t;                   // 16B-granule index 0..511
      int r = li >> 3, ck = li & 7;
      int cs = ck ^ (r & 7);
      const _Float16* src = xb + (size_t)(row0 + r) * CC + half * 64 + cs * 8;
      _Float16* dst = &lds[buf][i * 2048 + (t & 192) * 8];
      __builtin_amdgcn_global_load_lds((const __attribute__((address_space(1))) void*)src,
                                       (__attribute__((address_space(3))) void*)dst,
                                       16, 0, 0);
    }
  };

  f32x4 acc[2][4];
  #pragma unroll
  for (int m = 0; m < 2; ++m)
    #pragma unroll
    for (int n = 0; n < 4; ++n) acc[m][n] = (f32x4){0.f, 0.f, 0.f, 0.f};

  stage(0, Xs[0], 0);
  #pragma unroll
  for (int c = 0; c < KB * 2; ++c) {
    if (c + 1 < KB * 2) {
      stage((c + 1) & 1, Xs[(c + 1) >> 1], (c + 1) & 1);
      asm volatile("s_waitcnt vmcnt(2)" ::: "memory");
    } else {
      asm volatile("s_waitcnt vmcnt(0)" ::: "memory");
    }
    __builtin_amdgcn_sched_barrier(0);
    __builtin_amdgcn_s_barrier();
    const _Float16* __restrict__ lb = lds[c & 1];

    #pragma unroll
    for (int kk = 0; kk < 2; ++kk) {
      int kb = c * 2 + kk;
      h8 a[2], b[4];
      #pragma unroll
      for (int m = 0; m < 2; ++m) {
        int R = m0w + m * 16 + lr;
        a[m] = *reinterpret_cast<const h8*>(&lb[R * 64 + (((kk * 4 + lk) ^ (R & 7)) << 3)]);
      }
      #pragma unroll
      for (int n = 0; n < 4; ++n)
        b[n] = *reinterpret_cast<const h8*>(&Wp[((size_t)(kb * 8 + nb0 + n) * 64 + l) * 8]);
      #pragma unroll
      for (int m = 0; m < 2; ++m)
        #pragma unroll
        for (int n = 0; n < 4; ++n)
          acc[m][n] = __builtin_amdgcn_mfma_f32_16x16x32_f16(a[m], b[n], acc[m][n], 0, 0, 0);
    }
    __builtin_amdgcn_s_barrier();
  }

  int r0 = m0w + lk * 4;
  long rb = row0 + r0;
  #pragma unroll
  for (int m = 0; m < 2; ++m) {
    #pragma unroll
    for (int n = 0; n < 4; ++n) {
      int c = (nb0 + n) * 16 + lr;
      float bv = BR ? bias[c] : 0.0f;
      #pragma unroll
      for (int q = 0; q < 4; ++q) {
        float v = acc[m][n][q] + bv;
        if (BR) v = fmaxf(v, 0.0f);
        Y[(rb + m * 16 + q) * CC + c] = (_Float16)v;
      }
    }
  }
}

// ---------------- fused tail, M=64 tile (1564 blocks ~6/CU vs r20's 782=3/CU) ----
// stage X[64][128] -> GEMM1 -> LDS(pg) -> GEMM2 -> LDS(pg) -> wave-parallel head.

__global__ __launch_bounds__(256) void k_tail(const _Float16* __restrict__ X,
                                              const _Float16* __restrict__ WpM,
                                              const float* __restrict__ b_mlp,
                                              const float* __restrict__ W1,
                                              const float* __restrict__ b1,
                                              float* __restrict__ out) {
  __shared__ _Float16 lds[64 * 128];          // 16 KB
  int t = threadIdx.x;
  int w = t >> 6, l = t & 63;
  int lr = l & 15, lk = l >> 4;
  int m0w = (w & 1) * 32;
  int nb0 = (w >> 1) * 4;
  long row0 = (long)blockIdx.x * 64;

  // stage X tile (pre-swizzled source -> linear LDS; X-read perm = g ^ (r&7))
  #pragma unroll
  for (int i = 0; i < 4; ++i) {
    int li = i * 256 + t;                     // granule 0..1023
    int r = li >> 4, ck = li & 15;
    int cs = ck ^ (r & 7);
    const _Float16* src = X + (size_t)(row0 + r) * CC + cs * 8;
    _Float16* dst = &lds[i * 2048 + (t & 192) * 8];
    __builtin_amdgcn_global_load_lds((const __attribute__((address_space(1))) void*)src,
                                     (__attribute__((address_space(3))) void*)dst,
                                     16, 0, 0);
  }
  __syncthreads();

  f32x4 acc[2][4];
  #pragma unroll
  for (int ph = 0; ph < 2; ++ph) {
    #pragma unroll
    for (int m = 0; m < 2; ++m)
      #pragma unroll
      for (int n = 0; n < 4; ++n) acc[m][n] = (f32x4){0.f, 0.f, 0.f, 0.f};
    #pragma unroll
    for (int kk = 0; kk < 4; ++kk) {
      h8 a[2], b[4];
      #pragma unroll
      for (int m = 0; m < 2; ++m) {
        int R = m0w + m * 16 + lr;
        int g = kk * 4 + lk;
        int gp = (ph == 0) ? (g ^ (R & 7)) : pg(R, g);
        a[m] = *reinterpret_cast<const h8*>(&lds[R * 128 + gp * 8]);
      }
      #pragma unroll
      for (int n = 0; n < 4; ++n)
        b[n] = *reinterpret_cast<const h8*>(&WpM[((size_t)((ph * 4 + kk) * 8 + nb0 + n) * 64 + l) * 8]);
      #pragma unroll
      for (int m = 0; m < 2; ++m)
        #pragma unroll
        for (int n = 0; n < 4; ++n)
          acc[m][n] = __builtin_amdgcn_mfma_f32_16x16x32_f16(a[m], b[n], acc[m][n], 0, 0, 0);
    }
    __syncthreads();
    #pragma unroll
    for (int m = 0; m < 2; ++m) {
      #pragma unroll
      for (int n = 0; n < 4; ++n) {
        int c = (nb0 + n) * 16 + lr;
        float bv = b_mlp[ph * 128 + c];
        int g = c >> 3, eo = c & 7;
        #pragma unroll
        for (int q = 0; q < 4; ++q) {
          int R = m0w + m * 16 + lk * 4 + q;
          float v = fmaxf(acc[m][n][q] + bv, 0.0f);
          lds[R * 128 + pg(R, g) * 8 + eo] = (_Float16)v;
        }
      }
    }
    __syncthreads();
  }

  // head: lane l -> row w*16 + ps*4 + (l>>4), granule gH = l&15; 4 passes.
  int gH = l & 15;
  float w1s[8];
  #pragma unroll
  for (int q = 0; q < 8; ++q) w1s[q] = W1[gH * 8 + q];
  float b1v = b1[0];
  #pragma unroll
  for (int ps = 0; ps < 4; ++ps) {
    int R = w * 16 + ps * 4 + (l >> 4);
    h8 hv = *reinterpret_cast<const h8*>(&lds[R * 128 + pg(R, gH) * 8]);
    float s = 0.0f;
    #pragma unroll
    for (int q = 0; q < 8; ++q) s = fmaf((float)hv[q], w1s[q], s);
    s += __shfl_xor(s, 1);
    s += __shfl_xor(s, 2);
    s += __shfl_xor(s, 4);
    s += __shfl_xor(s, 8);
    long grow = row0 + R;
    if (gH == 0 && grow < NN) out[grow] = fmaxf(s + b1v, 0.0f);
  }
}

// ---------------- launch ----------------

extern "C" void kernel_launch(void* const* d_in, const int* in_sizes, int n_in,
                              void* d_out, int out_size, void* d_ws, size_t ws_size,
                              hipStream_t stream) {
  const float* x     = (const float*)d_in[0];
  const int*   ei    = (const int*)d_in[1];
  const float* W0    = (const float*)d_in[2];
  const float* b0    = (const float*)d_in[3];
  const float* W_tag = (const float*)d_in[4];
  const float* b_tag = (const float*)d_in[5];
  const float* W_mlp = (const float*)d_in[6];
  const float* b_mlp = (const float*)d_in[7];
  const float* W1    = (const float*)d_in[8];
  const float* b1    = (const float*)d_in[9];
  const int* row = ei;          // edge_index[0] = source
  const int* col = ei + NE;     // edge_index[1] = target

  char* p = (char*)d_ws;
  auto carve = [&](size_t bytes) { void* r = (void*)p; p += (bytes + 255) & ~(size_t)255; return r; };
  _Float16* hA   = (_Float16*)carve((size_t)NP * CC * 2);
  _Float16* hB   = (_Float16*)carve((size_t)NP * CC * 2);
  _Float16* x1   = (_Float16*)carve((size_t)NP * CC * 2);
  _Float16* x2   = (_Float16*)carve((size_t)NP * CC * 2);
  _Float16* x3   = (_Float16*)carve((size_t)NP * CC * 2);
  _Float16* WpT  = (_Float16*)carve((size_t)1024 * CC * 2);
  _Float16* WpM  = (_Float16*)carve((size_t)256 * CC * 2);
  float* dis     = (float*)carve((size_t)NP * 4);
  int*   dc      = (int*)carve((size_t)(NP + NN) * 4);
  int*   deg     = dc;
  int*   cnt     = dc + NP;
  int*   rowptr  = (int*)carve((size_t)(NP + 8) * 4);
  int*   bsum    = (int*)carve(512);
  int*   bsum2   = (int*)carve(512);
  int2*  csr     = (int2*)carve((size_t)NE * 8);

  k_zero<<<(DC_INT4 + 255) / 256, 256, 0, stream>>>((int4*)dc);

  k_deg<<<(NE + 255) / 256, 256, 0, stream>>>(col, deg);
  k_scan1<<<98, 1024, 0, stream>>>(deg, rowptr, bsum, dis);
  k_scan2<<<1, 128, 0, stream>>>(bsum, bsum2, rowptr);
  k_scan3<<<98, 1024, 0, stream>>>(rowptr, bsum2);
  k_fill<<<(NE + 255) / 256, 256, 0, stream>>>(row, col, dis, rowptr, cnt, csr);

  k_wconv2<<<(1280 * CC + 255) / 256, 256, 0, stream>>>(W_tag, W_mlp, WpT);

  k_lin0<<<NP * CC / 256, 256, 0, stream>>>(x, W0, b0, hA);

  const int GB64 = NP / 64;            // 1564 blocks (M=64 tiles)
  const int PB   = (NP / 4) * 64 / 256;

  _Float16* hc = hA;
  _Float16* hn = hB;
  for (int g = 0; g < 2; ++g) {
    k_prop<<<PB, 256, 0, stream>>>(rowptr, csr, hc, x1);
    k_prop<<<PB, 256, 0, stream>>>(rowptr, csr, x1, x2);
    k_prop<<<PB, 256, 0, stream>>>(rowptr, csr, x2, x3);
    k_mm<4, true><<<GB64, 256, 0, stream>>>(hc, x1, x2, x3, WpT + (size_t)g * 512 * CC,
                                            b_tag + (size_t)g * CC, hn);
    _Float16* tmp = hc; hc = hn; hn = tmp;
  }

  k_tail<<<GB64, 256, 0, stream>>>(hc, WpM, b_mlp, W1, b1, (float*)d_out);
}